// Round 6
// baseline (69.541 us; speedup 1.0000x reference)
//
#include <hip/hip_runtime.h>

#define BATCH 8192

typedef __attribute__((ext_vector_type(8))) short bf16x8;
typedef __attribute__((ext_vector_type(4))) float f32x4;

__device__ __forceinline__ unsigned short f2bf(float f) {
    unsigned int u = __float_as_uint(f);
    u += 0x7fffu + ((u >> 16) & 1u);      // RTNE
    return (unsigned short)(u >> 16);
}
__device__ __forceinline__ float rfl(float v) {
    return __int_as_float(__builtin_amdgcn_readfirstlane(__float_as_int(v)));
}

// ---------------------------------------------------------------------------
// Single fused kernel, 256 blocks x 256 threads (1 block/CU -> all co-resident,
// so the device-scope flag barrier cannot deadlock).
// Phase A: wave 0 computes U column c=blockIdx.x (R3/R5-verified circuit) ->
//          Ub[512][256] bf16 in d_ws (rows 0-255 Re, 256-511 Im);
//          waves 1-2 build the block's 32-sample psi (product state) in LDS.
// Barrier: release-fence + atomic flag (agent scope), tid0 spins, acquire.
// Phase B: R5-verified MFMA GEMM (A=Ub from global/L2, B=psi from LDS) with
//          fused |.|^2 + signed-sum epilogue. Amp-index bit (7-w) = wire w.
// ---------------------------------------------------------------------------
__global__ __launch_bounds__(256) void fused(const float* __restrict__ x,
                                             const float* __restrict__ w,
                                             float* __restrict__ out,
                                             unsigned short* __restrict__ Ub,
                                             unsigned int* __restrict__ flag)
{
    __shared__ unsigned short psi[32 * 264];   // 32 samples x 256 amps, stride 264 (528B)
    __shared__ float Ps[16][289];              // epilogue partials
    const int tid  = threadIdx.x;
    const int wid  = tid >> 6;
    const int lane = tid & 63;
    const int bid  = blockIdx.x;

    if (wid == 0) {
        // ---- U column c = bid; lane bits l5..l0 = wires 0-5, reg k1k0 = wires 6,7
        const int l = lane;
        const int c = bid;
        float re[4], im[4];
        const bool ls = (l == (c >> 2));
        #pragma unroll
        for (int k = 0; k < 4; ++k) {
            re[k] = (ls && ((c & 3) == k)) ? 1.0f : 0.0f;
            im[k] = 0.0f;
        }
        const int  src = (l ^ (l >> 1)) & 63;
        const bool c5  = (l & 1);
        #pragma unroll 1
        for (int layer = 0; layer < 4; ++layer) {
            const float* wl = w + layer * 16;
            float tr[4], ti[4];
            #pragma unroll
            for (int k = 0; k < 4; ++k) {
                tr[k] = __shfl(re[k], src, 64);
                ti[k] = __shfl(im[k], src, 64);
            }
            re[0] = c5 ? tr[2] : tr[0];  im[0] = c5 ? ti[2] : ti[0];
            re[1] = c5 ? tr[3] : tr[1];  im[1] = c5 ? ti[3] : ti[1];
            re[2] = c5 ? tr[1] : tr[3];  im[2] = c5 ? ti[1] : ti[3];
            re[3] = c5 ? tr[0] : tr[2];  im[3] = c5 ? ti[0] : ti[2];
            re[1] = __shfl_xor(re[1], 32, 64); im[1] = __shfl_xor(im[1], 32, 64);
            re[3] = __shfl_xor(re[3], 32, 64); im[3] = __shfl_xor(im[3], 32, 64);
            #pragma unroll
            for (int i = 0; i < 6; ++i) {
                float cth = __cosf(0.5f * wl[2*i]),   sth = __sinf(0.5f * wl[2*i]);
                float cph = __cosf(0.5f * wl[2*i+1]), sph = __sinf(0.5f * wl[2*i+1]);
                float Ar = rfl(cth * cph), SZ = rfl(sth * sph);
                float sgn = (l & (32 >> i)) ? 1.0f : -1.0f;
                float Ai = sgn * rfl(cth * sph);
                float Br = sgn * rfl(sth * cph);
                const int m = 32 >> i;
                #pragma unroll
                for (int k = 0; k < 4; ++k) {
                    float br = __shfl_xor(re[k], m, 64);
                    float bi = __shfl_xor(im[k], m, 64);
                    float ar = re[k], ai = im[k];
                    re[k] = Ar*ar - Ai*ai + Br*br + SZ*bi;
                    im[k] = Ar*ai + Ai*ar + Br*bi - SZ*br;
                }
            }
            #pragma unroll
            for (int i = 0; i < 2; ++i) {
                float cy = rfl(__cosf(0.5f * wl[12 + 2*i]));
                float sy = rfl(__sinf(0.5f * wl[12 + 2*i]));
                float cf = rfl(__cosf(wl[13 + 2*i]));
                float sf = rfl(__sinf(wl[13 + 2*i]));
                const int mk = 2 >> i;
                #pragma unroll
                for (int k = 0; k < 4; ++k) {
                    if (!(k & mk)) continue;
                    float r = re[k], q = im[k];
                    re[k] = r * cf - q * sf;
                    im[k] = q * cf + r * sf;
                }
                #pragma unroll
                for (int k = 0; k < 4; ++k) {
                    if (k & mk) continue;
                    int k1 = k | mk;
                    float ar = re[k], ai = im[k], br = re[k1], bi = im[k1];
                    re[k]  = cy * ar - sy * br;
                    im[k]  = cy * ai - sy * bi;
                    re[k1] = sy * ar + cy * br;
                    im[k1] = sy * ai + cy * bi;
                }
            }
        }
        #pragma unroll
        for (int k = 0; k < 4; ++k) {
            int i = l * 4 + k;
            Ub[i * 256 + c]         = f2bf(re[k]);
            Ub[(256 + i) * 256 + c] = f2bf(im[k]);
        }
        __threadfence();   // release: make U column device-visible before flag
    } else if (wid <= 2) {
        // ---- psi for this block's 32 samples; thread u: sample u>>2, quarter u&3
        const int u = tid - 64;
        const int s = u >> 2;
        const int q = u & 3;
        const float4* xv = (const float4*)(x + (bid * 32 + s) * 8);
        float4 x0 = xv[0], x1 = xv[1];
        float xe[8] = {x0.x, x0.y, x0.z, x0.w, x1.x, x1.y, x1.z, x1.w};
        float ce[8], se[8];
        #pragma unroll
        for (int i = 0; i < 8; ++i) {
            float a = 0.5f * (xe[i] + w[2 * i]);
            ce[i] = __cosf(a); se[i] = __sinf(a);
        }
        float p45[4] = {ce[4]*ce[5], ce[4]*se[5], se[4]*ce[5], se[4]*se[5]};
        float p67[4] = {ce[6]*ce[7], ce[6]*se[7], se[6]*ce[7], se[6]*se[7]};
        #pragma unroll
        for (int j1 = q * 4; j1 < q * 4 + 4; ++j1) {
            float A1 = ((j1&8)?se[0]:ce[0]) * ((j1&4)?se[1]:ce[1])
                     * ((j1&2)?se[2]:ce[2]) * ((j1&1)?se[3]:ce[3]);
            unsigned int wbuf[8];
            #pragma unroll
            for (int p = 0; p < 8; ++p) {
                int ja = 2*p, jb = 2*p + 1;
                float va = A1 * p45[ja >> 2] * p67[ja & 3];
                float vb = A1 * p45[jb >> 2] * p67[jb & 3];
                wbuf[p] = (unsigned int)f2bf(va) | ((unsigned int)f2bf(vb) << 16);
            }
            uint4* dst = (uint4*)((char*)psi + s * 528 + j1 * 32);
            dst[0] = make_uint4(wbuf[0], wbuf[1], wbuf[2], wbuf[3]);
            dst[1] = make_uint4(wbuf[4], wbuf[5], wbuf[6], wbuf[7]);
        }
    }
    __syncthreads();
    if (tid == 0) {
        __hip_atomic_fetch_add(flag, 1u, __ATOMIC_RELEASE, __HIP_MEMORY_SCOPE_AGENT);
        while (__hip_atomic_load(flag, __ATOMIC_ACQUIRE, __HIP_MEMORY_SCOPE_AGENT) < 256u)
            __builtin_amdgcn_s_sleep(4);
    }
    __syncthreads();
    __threadfence();   // acquire side: invalidate stale L1/L2 before reading Ub

    // ---- GEMM: C[512][32] = U * psi, fused measurement epilogue (R5-verified)
    const int mrow = lane & 15;
    const int kgrp = lane >> 4;
    const int s0   = bid * 32;

    f32x4 acc[8][2];
    #pragma unroll
    for (int a = 0; a < 8; ++a)
        #pragma unroll
        for (int b = 0; b < 2; ++b)
            acc[a][b] = (f32x4){0.f, 0.f, 0.f, 0.f};

    #pragma unroll
    for (int ks = 0; ks < 8; ++ks) {
        const int k0 = ks * 32 + kgrp * 8;
        bf16x8 bfr0 = *(const bf16x8*)(psi + mrow * 264 + k0);
        bf16x8 bfr1 = *(const bf16x8*)(psi + (16 + mrow) * 264 + k0);
        #pragma unroll
        for (int mt = 0; mt < 8; ++mt) {
            const int row = (mt < 4) ? (wid * 64 + mt * 16 + mrow)
                                     : (256 + wid * 64 + (mt - 4) * 16 + mrow);
            bf16x8 afr = *(const bf16x8*)(Ub + row * 256 + k0);
            acc[mt][0] = __builtin_amdgcn_mfma_f32_16x16x32_bf16(afr, bfr0, acc[mt][0], 0, 0, 0);
            acc[mt][1] = __builtin_amdgcn_mfma_f32_16x16x32_bf16(afr, bfr1, acc[mt][1], 0, 0, 0);
        }
    }

    // epilogue: amp index i = 64*wid + mtl*16 + kgrp*4 + r  (bit 7-w = wire w)
    const int ct = wid * 4 + kgrp;
    #pragma unroll
    for (int nt = 0; nt < 2; ++nt) {
        float am[4], r2m[4], r1m[4];
        #pragma unroll
        for (int mtl = 0; mtl < 4; ++mtl) {
            float p0 = acc[mtl][nt][0]*acc[mtl][nt][0] + acc[mtl+4][nt][0]*acc[mtl+4][nt][0];
            float p1 = acc[mtl][nt][1]*acc[mtl][nt][1] + acc[mtl+4][nt][1]*acc[mtl+4][nt][1];
            float p2 = acc[mtl][nt][2]*acc[mtl][nt][2] + acc[mtl+4][nt][2]*acc[mtl+4][nt][2];
            float p3 = acc[mtl][nt][3]*acc[mtl][nt][3] + acc[mtl+4][nt][3]*acc[mtl+4][nt][3];
            float t0 = p0 + p1, t1 = p2 + p3;
            am[mtl]  = t0 + t1;
            r2m[mtl] = t0 - t1;                    // wire6: sign by r>>1
            r1m[mtl] = (p0 - p1) + (p2 - p3);      // wire7: sign by r&1
        }
        float ps = (am[0] + am[1]) + (am[2] + am[3]);
        float m2 = (am[0] + am[1]) - (am[2] + am[3]);    // wire2: mtl>>1
        float m3 = (am[0] - am[1]) + (am[2] - am[3]);    // wire3: mtl&1
        float m6 = (r2m[0] + r2m[1]) + (r2m[2] + r2m[3]);
        float m7 = (r1m[0] + r1m[1]) + (r1m[2] + r1m[3]);
        float m0 = (wid >= 2) ? -ps : ps;                // wire0: bit7
        float m1 = (wid & 1)  ? -ps : ps;                // wire1: bit6
        float m4 = (kgrp & 2) ? -ps : ps;                // wire4: bit3
        float m5 = (kgrp & 1) ? -ps : ps;                // wire5: bit2
        const int snt = nt * 16 + mrow;
        float* pp = &Ps[ct][snt * 9];
        pp[0]=m0; pp[1]=m1; pp[2]=m2; pp[3]=m3; pp[4]=m4; pp[5]=m5; pp[6]=m6; pp[7]=m7;
    }
    __syncthreads();
    if (tid < 32) {
        const int s = tid;
        float r[8] = {0,0,0,0,0,0,0,0};
        #pragma unroll
        for (int uu = 0; uu < 16; ++uu)
            #pragma unroll
            for (int e = 0; e < 8; ++e)
                r[e] += Ps[uu][s * 9 + e];
        float4* o = (float4*)(out + (s0 + s) * 8);
        o[0] = make_float4(r[0], r[1], r[2], r[3]);
        o[1] = make_float4(r[4], r[5], r[6], r[7]);
    }
}

extern "C" void kernel_launch(void* const* d_in, const int* in_sizes, int n_in,
                              void* d_out, int out_size, void* d_ws, size_t ws_size,
                              hipStream_t stream)
{
    const float* x = (const float*)d_in[0];
    const float* w = (const float*)d_in[1];
    unsigned int*   flag = (unsigned int*)d_ws;
    unsigned short* Ub   = (unsigned short*)((char*)d_ws + 1024);   // 256 KiB
    hipMemsetAsync(d_ws, 0, 4, stream);                             // reset barrier flag
    fused<<<256, 256, 0, stream>>>(x, w, (float*)d_out, Ub, flag);
}

// Round 7
// 24.656 us; speedup vs baseline: 2.8204x; 2.8204x over previous
//
#include <hip/hip_runtime.h>

#define BATCH 8192

typedef __attribute__((ext_vector_type(8))) short bf16x8;
typedef __attribute__((ext_vector_type(4))) float f32x4;

__device__ __forceinline__ unsigned short f2bf(float f) {
    unsigned int u = __float_as_uint(f);
    u += 0x7fffu + ((u >> 16) & 1u);      // RTNE
    return (unsigned short)(u >> 16);
}
__device__ __forceinline__ float rfl(float v) {
    return __int_as_float(__builtin_amdgcn_readfirstlane(__float_as_int(v)));
}

// ---------------------------------------------------------------------------
// Kernel 1: U columns. 64 blocks x 4 waves; wave -> column c.
// Lane bits l5..l0 = wires 0-5, reg bits k1k0 = wires 6,7 (R3/R5-verified).
// Ub[512][256] bf16: rows 0-255 Re, rows 256-511 Im; column c = basis state.
// ---------------------------------------------------------------------------
__global__ __launch_bounds__(256) void ukern(const float* __restrict__ w,
                                             unsigned short* __restrict__ Ub)
{
    const int l = threadIdx.x & 63;
    const int c = blockIdx.x * 4 + (threadIdx.x >> 6);
    float re[4], im[4];
    const bool ls = (l == (c >> 2));
    #pragma unroll
    for (int k = 0; k < 4; ++k) {
        re[k] = (ls && ((c & 3) == k)) ? 1.0f : 0.0f;
        im[k] = 0.0f;
    }
    const int  src = (l ^ (l >> 1)) & 63;
    const bool c5  = (l & 1);
    #pragma unroll 1
    for (int layer = 0; layer < 4; ++layer) {
        const float* wl = w + layer * 16;
        float tr[4], ti[4];
        #pragma unroll
        for (int k = 0; k < 4; ++k) {
            tr[k] = __shfl(re[k], src, 64);
            ti[k] = __shfl(im[k], src, 64);
        }
        re[0] = c5 ? tr[2] : tr[0];  im[0] = c5 ? ti[2] : ti[0];
        re[1] = c5 ? tr[3] : tr[1];  im[1] = c5 ? ti[3] : ti[1];
        re[2] = c5 ? tr[1] : tr[3];  im[2] = c5 ? ti[1] : ti[3];
        re[3] = c5 ? tr[0] : tr[2];  im[3] = c5 ? ti[0] : ti[2];
        re[1] = __shfl_xor(re[1], 32, 64); im[1] = __shfl_xor(im[1], 32, 64);
        re[3] = __shfl_xor(re[3], 32, 64); im[3] = __shfl_xor(im[3], 32, 64);
        #pragma unroll
        for (int i = 0; i < 6; ++i) {
            float cth = __cosf(0.5f * wl[2*i]),   sth = __sinf(0.5f * wl[2*i]);
            float cph = __cosf(0.5f * wl[2*i+1]), sph = __sinf(0.5f * wl[2*i+1]);
            float Ar = rfl(cth * cph), SZ = rfl(sth * sph);
            float sgn = (l & (32 >> i)) ? 1.0f : -1.0f;
            float Ai = sgn * rfl(cth * sph);
            float Br = sgn * rfl(sth * cph);
            const int m = 32 >> i;
            #pragma unroll
            for (int k = 0; k < 4; ++k) {
                float br = __shfl_xor(re[k], m, 64);
                float bi = __shfl_xor(im[k], m, 64);
                float ar = re[k], ai = im[k];
                re[k] = Ar*ar - Ai*ai + Br*br + SZ*bi;
                im[k] = Ar*ai + Ai*ar + Br*bi - SZ*br;
            }
        }
        #pragma unroll
        for (int i = 0; i < 2; ++i) {
            float cy = rfl(__cosf(0.5f * wl[12 + 2*i]));
            float sy = rfl(__sinf(0.5f * wl[12 + 2*i]));
            float cf = rfl(__cosf(wl[13 + 2*i]));
            float sf = rfl(__sinf(wl[13 + 2*i]));
            const int mk = 2 >> i;
            #pragma unroll
            for (int k = 0; k < 4; ++k) {
                if (!(k & mk)) continue;
                float r = re[k], q = im[k];
                re[k] = r * cf - q * sf;
                im[k] = q * cf + r * sf;
            }
            #pragma unroll
            for (int k = 0; k < 4; ++k) {
                if (k & mk) continue;
                int k1 = k | mk;
                float ar = re[k], ai = im[k], br = re[k1], bi = im[k1];
                re[k]  = cy * ar - sy * br;
                im[k]  = cy * ai - sy * bi;
                re[k1] = sy * ar + cy * br;
                im[k1] = sy * ai + cy * bi;
            }
        }
    }
    #pragma unroll
    for (int k = 0; k < 4; ++k) {
        int i = l * 4 + k;
        Ub[i * 256 + c]         = f2bf(re[k]);
        Ub[(256 + i) * 256 + c] = f2bf(im[k]);
    }
}

// ---------------------------------------------------------------------------
// Kernel 2: per block of 32 samples: build psi in LDS (product state), then
// C[512][32] = U * psi via MFMA with fused |.|^2 + signed-sum epilogue.
// Amp-index bit (7-w) = wire w. (R5/R6-verified GEMM + epilogue.)
// ---------------------------------------------------------------------------
__global__ __launch_bounds__(256) void qmain(const float* __restrict__ x,
                                             const float* __restrict__ w,
                                             const unsigned short* __restrict__ Ub,
                                             float* __restrict__ out)
{
    __shared__ unsigned short psi[32 * 264];   // 32 samples x 256 amps, stride 264 (528B)
    __shared__ float Ps[16][289];              // epilogue partials
    const int tid  = threadIdx.x;
    const int wid  = tid >> 6;
    const int lane = tid & 63;
    const int bid  = blockIdx.x;

    // ---- psi: thread t -> sample t>>3, j-chunk (t&7)*32 (R5 prep pattern) ----
    {
        const int s  = tid >> 3;
        const float4* xv = (const float4*)(x + (bid * 32 + s) * 8);
        float4 x0 = xv[0], x1 = xv[1];
        float xe[8] = {x0.x, x0.y, x0.z, x0.w, x1.x, x1.y, x1.z, x1.w};
        float ce[8], se[8];
        #pragma unroll
        for (int i = 0; i < 8; ++i) {
            float a = 0.5f * (xe[i] + w[2 * i]);
            ce[i] = __cosf(a); se[i] = __sinf(a);
        }
        float p45[4] = {ce[4]*ce[5], ce[4]*se[5], se[4]*ce[5], se[4]*se[5]};
        float p67[4] = {ce[6]*ce[7], ce[6]*se[7], se[6]*ce[7], se[6]*se[7]};
        const int j1b = (tid & 7) * 2;
        #pragma unroll
        for (int jo = 0; jo < 2; ++jo) {
            const int j1 = j1b + jo;
            float A1 = ((j1&8)?se[0]:ce[0]) * ((j1&4)?se[1]:ce[1])
                     * ((j1&2)?se[2]:ce[2]) * ((j1&1)?se[3]:ce[3]);
            unsigned int wbuf[8];
            #pragma unroll
            for (int p = 0; p < 8; ++p) {
                int ja = 2*p, jb = 2*p + 1;
                float va = A1 * p45[ja >> 2] * p67[ja & 3];
                float vb = A1 * p45[jb >> 2] * p67[jb & 3];
                wbuf[p] = (unsigned int)f2bf(va) | ((unsigned int)f2bf(vb) << 16);
            }
            uint4* dst = (uint4*)((char*)psi + s * 528 + j1 * 32);
            dst[0] = make_uint4(wbuf[0], wbuf[1], wbuf[2], wbuf[3]);
            dst[1] = make_uint4(wbuf[4], wbuf[5], wbuf[6], wbuf[7]);
        }
    }
    __syncthreads();

    // ---- GEMM: A = Ub rows (global/L2), B = psi (LDS) ----
    const int mrow = lane & 15;
    const int kgrp = lane >> 4;
    const int s0   = bid * 32;

    f32x4 acc[8][2];
    #pragma unroll
    for (int a = 0; a < 8; ++a)
        #pragma unroll
        for (int b = 0; b < 2; ++b)
            acc[a][b] = (f32x4){0.f, 0.f, 0.f, 0.f};

    #pragma unroll
    for (int ks = 0; ks < 8; ++ks) {
        const int k0 = ks * 32 + kgrp * 8;
        bf16x8 bfr0 = *(const bf16x8*)(psi + mrow * 264 + k0);
        bf16x8 bfr1 = *(const bf16x8*)(psi + (16 + mrow) * 264 + k0);
        #pragma unroll
        for (int mt = 0; mt < 8; ++mt) {
            const int row = (mt < 4) ? (wid * 64 + mt * 16 + mrow)
                                     : (256 + wid * 64 + (mt - 4) * 16 + mrow);
            bf16x8 afr = *(const bf16x8*)(Ub + row * 256 + k0);
            acc[mt][0] = __builtin_amdgcn_mfma_f32_16x16x32_bf16(afr, bfr0, acc[mt][0], 0, 0, 0);
            acc[mt][1] = __builtin_amdgcn_mfma_f32_16x16x32_bf16(afr, bfr1, acc[mt][1], 0, 0, 0);
        }
    }

    // ---- epilogue: amp index i = 64*wid + mtl*16 + kgrp*4 + r ----
    const int ct = wid * 4 + kgrp;
    #pragma unroll
    for (int nt = 0; nt < 2; ++nt) {
        float am[4], r2m[4], r1m[4];
        #pragma unroll
        for (int mtl = 0; mtl < 4; ++mtl) {
            float p0 = acc[mtl][nt][0]*acc[mtl][nt][0] + acc[mtl+4][nt][0]*acc[mtl+4][nt][0];
            float p1 = acc[mtl][nt][1]*acc[mtl][nt][1] + acc[mtl+4][nt][1]*acc[mtl+4][nt][1];
            float p2 = acc[mtl][nt][2]*acc[mtl][nt][2] + acc[mtl+4][nt][2]*acc[mtl+4][nt][2];
            float p3 = acc[mtl][nt][3]*acc[mtl][nt][3] + acc[mtl+4][nt][3]*acc[mtl+4][nt][3];
            float t0 = p0 + p1, t1 = p2 + p3;
            am[mtl]  = t0 + t1;
            r2m[mtl] = t0 - t1;                    // wire6: sign by r>>1
            r1m[mtl] = (p0 - p1) + (p2 - p3);      // wire7: sign by r&1
        }
        float ps = (am[0] + am[1]) + (am[2] + am[3]);
        float m2 = (am[0] + am[1]) - (am[2] + am[3]);    // wire2: mtl>>1
        float m3 = (am[0] - am[1]) + (am[2] - am[3]);    // wire3: mtl&1
        float m6 = (r2m[0] + r2m[1]) + (r2m[2] + r2m[3]);
        float m7 = (r1m[0] + r1m[1]) + (r1m[2] + r1m[3]);
        float m0 = (wid >= 2) ? -ps : ps;                // wire0: bit7
        float m1 = (wid & 1)  ? -ps : ps;                // wire1: bit6
        float m4 = (kgrp & 2) ? -ps : ps;                // wire4: bit3
        float m5 = (kgrp & 1) ? -ps : ps;                // wire5: bit2
        const int snt = nt * 16 + mrow;
        float* pp = &Ps[ct][snt * 9];
        pp[0]=m0; pp[1]=m1; pp[2]=m2; pp[3]=m3; pp[4]=m4; pp[5]=m5; pp[6]=m6; pp[7]=m7;
    }
    __syncthreads();
    if (tid < 32) {
        const int s = tid;
        float r[8] = {0,0,0,0,0,0,0,0};
        #pragma unroll
        for (int uu = 0; uu < 16; ++uu)
            #pragma unroll
            for (int e = 0; e < 8; ++e)
                r[e] += Ps[uu][s * 9 + e];
        float4* o = (float4*)(out + (s0 + s) * 8);
        o[0] = make_float4(r[0], r[1], r[2], r[3]);
        o[1] = make_float4(r[4], r[5], r[6], r[7]);
    }
}

extern "C" void kernel_launch(void* const* d_in, const int* in_sizes, int n_in,
                              void* d_out, int out_size, void* d_ws, size_t ws_size,
                              hipStream_t stream)
{
    const float* x = (const float*)d_in[0];
    const float* w = (const float*)d_in[1];
    unsigned short* Ub = (unsigned short*)d_ws;   // 256 KiB
    ukern<<<64, 256, 0, stream>>>(w, Ub);
    qmain<<<256, 256, 0, stream>>>(x, w, Ub, (float*)d_out);
}

// Round 8
// 23.429 us; speedup vs baseline: 2.9681x; 1.0524x over previous
//
#include <hip/hip_runtime.h>

#define BATCH 8192

typedef __attribute__((ext_vector_type(8))) short bf16x8;
typedef __attribute__((ext_vector_type(4))) float f32x4;

__device__ __forceinline__ unsigned short f2bf(float f) {
    unsigned int u = __float_as_uint(f);
    u += 0x7fffu + ((u >> 16) & 1u);      // RTNE
    return (unsigned short)(u >> 16);
}
__device__ __forceinline__ float rfl(float v) {
    return __int_as_float(__builtin_amdgcn_readfirstlane(__float_as_int(v)));
}

// ---------------------------------------------------------------------------
// Kernel 1 (unchanged, R5/R7-verified): U columns, 64 blocks x 4 waves.
// Ub[512][256] bf16: rows 0-255 Re, rows 256-511 Im; column c = basis state.
// ---------------------------------------------------------------------------
__global__ __launch_bounds__(256) void ukern(const float* __restrict__ w,
                                             unsigned short* __restrict__ Ub)
{
    const int l = threadIdx.x & 63;
    const int c = blockIdx.x * 4 + (threadIdx.x >> 6);
    float re[4], im[4];
    const bool ls = (l == (c >> 2));
    #pragma unroll
    for (int k = 0; k < 4; ++k) {
        re[k] = (ls && ((c & 3) == k)) ? 1.0f : 0.0f;
        im[k] = 0.0f;
    }
    const int  src = (l ^ (l >> 1)) & 63;
    const bool c5  = (l & 1);
    #pragma unroll 1
    for (int layer = 0; layer < 4; ++layer) {
        const float* wl = w + layer * 16;
        float tr[4], ti[4];
        #pragma unroll
        for (int k = 0; k < 4; ++k) {
            tr[k] = __shfl(re[k], src, 64);
            ti[k] = __shfl(im[k], src, 64);
        }
        re[0] = c5 ? tr[2] : tr[0];  im[0] = c5 ? ti[2] : ti[0];
        re[1] = c5 ? tr[3] : tr[1];  im[1] = c5 ? ti[3] : ti[1];
        re[2] = c5 ? tr[1] : tr[3];  im[2] = c5 ? ti[1] : ti[3];
        re[3] = c5 ? tr[0] : tr[2];  im[3] = c5 ? ti[0] : ti[2];
        re[1] = __shfl_xor(re[1], 32, 64); im[1] = __shfl_xor(im[1], 32, 64);
        re[3] = __shfl_xor(re[3], 32, 64); im[3] = __shfl_xor(im[3], 32, 64);
        #pragma unroll
        for (int i = 0; i < 6; ++i) {
            float cth = __cosf(0.5f * wl[2*i]),   sth = __sinf(0.5f * wl[2*i]);
            float cph = __cosf(0.5f * wl[2*i+1]), sph = __sinf(0.5f * wl[2*i+1]);
            float Ar = rfl(cth * cph), SZ = rfl(sth * sph);
            float sgn = (l & (32 >> i)) ? 1.0f : -1.0f;
            float Ai = sgn * rfl(cth * sph);
            float Br = sgn * rfl(sth * cph);
            const int m = 32 >> i;
            #pragma unroll
            for (int k = 0; k < 4; ++k) {
                float br = __shfl_xor(re[k], m, 64);
                float bi = __shfl_xor(im[k], m, 64);
                float ar = re[k], ai = im[k];
                re[k] = Ar*ar - Ai*ai + Br*br + SZ*bi;
                im[k] = Ar*ai + Ai*ar + Br*bi - SZ*br;
            }
        }
        #pragma unroll
        for (int i = 0; i < 2; ++i) {
            float cy = rfl(__cosf(0.5f * wl[12 + 2*i]));
            float sy = rfl(__sinf(0.5f * wl[12 + 2*i]));
            float cf = rfl(__cosf(wl[13 + 2*i]));
            float sf = rfl(__sinf(wl[13 + 2*i]));
            const int mk = 2 >> i;
            #pragma unroll
            for (int k = 0; k < 4; ++k) {
                if (!(k & mk)) continue;
                float r = re[k], q = im[k];
                re[k] = r * cf - q * sf;
                im[k] = q * cf + r * sf;
            }
            #pragma unroll
            for (int k = 0; k < 4; ++k) {
                if (k & mk) continue;
                int k1 = k | mk;
                float ar = re[k], ai = im[k], br = re[k1], bi = im[k1];
                re[k]  = cy * ar - sy * br;
                im[k]  = cy * ai - sy * bi;
                re[k1] = sy * ar + cy * br;
                im[k1] = sy * ai + cy * bi;
            }
        }
    }
    #pragma unroll
    for (int k = 0; k < 4; ++k) {
        int i = l * 4 + k;
        Ub[i * 256 + c]         = f2bf(re[k]);
        Ub[(256 + i) * 256 + c] = f2bf(im[k]);
    }
}

// ---------------------------------------------------------------------------
// Kernel 2: 256 blocks x 512 threads (8 waves, 2/SIMD).
// Phase 0: 256 threads compute per-(sample,wire) sincos once -> trg LDS.
// Phase 1: 512 threads build psi (32 samples x 256 amps bf16) in LDS.
// Phase 2: GEMM C[512][32] = U * psi; wave wid owns amps [32*wid, 32*wid+32)
//          (2 Re M-tiles + 2 Im M-tiles), fused |.|^2 + signed-sum epilogue.
// Amp-index bit (7-w) = wire w: wid = bits 7..5, mtl = bit 4, kgrp = bits 3..2,
// r = bits 1..0.
// ---------------------------------------------------------------------------
__global__ __launch_bounds__(512) void qmain(const float* __restrict__ x,
                                             const float* __restrict__ w,
                                             const unsigned short* __restrict__ Ub,
                                             float* __restrict__ out)
{
    __shared__ float trg[32][17];              // [sample][wire]=cos, [8+wire]=sin
    __shared__ unsigned short psi[32 * 264];   // 32 samples x 256 amps, stride 264
    __shared__ float Ps[32][289];              // epilogue partials
    const int tid  = threadIdx.x;
    const int wid  = tid >> 6;
    const int lane = tid & 63;
    const int bid  = blockIdx.x;
    const int s0   = bid * 32;

    // ---- phase 0: trig, one (sample,wire) pair per thread ----
    if (tid < 256) {
        const int s  = tid >> 3;
        const int wi = tid & 7;
        float a = 0.5f * (x[(s0 + s) * 8 + wi] + w[2 * wi]);
        trg[s][wi]     = __cosf(a);
        trg[s][8 + wi] = __sinf(a);
    }
    __syncthreads();

    // ---- phase 1: psi chunk (16 amps) per thread ----
    {
        const int s  = tid >> 4;
        const int j1 = tid & 15;
        float c0 = trg[s][0], c1 = trg[s][1], c2 = trg[s][2], c3 = trg[s][3];
        float s0w = trg[s][8], s1w = trg[s][9], s2w = trg[s][10], s3w = trg[s][11];
        float A1 = ((j1 & 8) ? s0w : c0) * ((j1 & 4) ? s1w : c1)
                 * ((j1 & 2) ? s2w : c2) * ((j1 & 1) ? s3w : c3);
        float c4 = trg[s][4], c5 = trg[s][5], c6 = trg[s][6], c7 = trg[s][7];
        float s4 = trg[s][12], s5 = trg[s][13], s6 = trg[s][14], s7 = trg[s][15];
        float q45[4] = {A1 * c4 * c5, A1 * c4 * s5, A1 * s4 * c5, A1 * s4 * s5};
        float p67[4] = {c6 * c7, c6 * s7, s6 * c7, s6 * s7};
        unsigned int wbuf[8];
        #pragma unroll
        for (int p = 0; p < 8; ++p) {
            int ja = 2 * p, jb = 2 * p + 1;
            float va = q45[ja >> 2] * p67[ja & 3];
            float vb = q45[jb >> 2] * p67[jb & 3];
            wbuf[p] = (unsigned int)f2bf(va) | ((unsigned int)f2bf(vb) << 16);
        }
        uint4* dst = (uint4*)((char*)psi + s * 528 + j1 * 32);
        dst[0] = make_uint4(wbuf[0], wbuf[1], wbuf[2], wbuf[3]);
        dst[1] = make_uint4(wbuf[4], wbuf[5], wbuf[6], wbuf[7]);
    }
    __syncthreads();

    // ---- phase 2: GEMM, wave wid owns amps [32*wid, 32*wid+32) ----
    const int mrow = lane & 15;
    const int kgrp = lane >> 4;

    f32x4 acc[4][2];   // mt: 0,1 = Re tiles; 2,3 = Im tiles; nt 0..1
    #pragma unroll
    for (int a = 0; a < 4; ++a)
        #pragma unroll
        for (int b = 0; b < 2; ++b)
            acc[a][b] = (f32x4){0.f, 0.f, 0.f, 0.f};

    #pragma unroll
    for (int ks = 0; ks < 8; ++ks) {
        const int k0 = ks * 32 + kgrp * 8;
        bf16x8 bfr0 = *(const bf16x8*)(psi + mrow * 264 + k0);
        bf16x8 bfr1 = *(const bf16x8*)(psi + (16 + mrow) * 264 + k0);
        #pragma unroll
        for (int mt = 0; mt < 4; ++mt) {
            const int row = (mt < 2) ? (wid * 32 + mt * 16 + mrow)
                                     : (256 + wid * 32 + (mt - 2) * 16 + mrow);
            bf16x8 afr = *(const bf16x8*)(Ub + row * 256 + k0);
            acc[mt][0] = __builtin_amdgcn_mfma_f32_16x16x32_bf16(afr, bfr0, acc[mt][0], 0, 0, 0);
            acc[mt][1] = __builtin_amdgcn_mfma_f32_16x16x32_bf16(afr, bfr1, acc[mt][1], 0, 0, 0);
        }
    }

    // ---- epilogue: amp = 32*wid + mtl*16 + kgrp*4 + r ----
    const int ct = wid * 4 + kgrp;
    #pragma unroll
    for (int nt = 0; nt < 2; ++nt) {
        float am[2], r2m[2], r1m[2];
        #pragma unroll
        for (int mtl = 0; mtl < 2; ++mtl) {
            float p0 = acc[mtl][nt][0]*acc[mtl][nt][0] + acc[mtl+2][nt][0]*acc[mtl+2][nt][0];
            float p1 = acc[mtl][nt][1]*acc[mtl][nt][1] + acc[mtl+2][nt][1]*acc[mtl+2][nt][1];
            float p2 = acc[mtl][nt][2]*acc[mtl][nt][2] + acc[mtl+2][nt][2]*acc[mtl+2][nt][2];
            float p3 = acc[mtl][nt][3]*acc[mtl][nt][3] + acc[mtl+2][nt][3]*acc[mtl+2][nt][3];
            float t0 = p0 + p1, t1 = p2 + p3;
            am[mtl]  = t0 + t1;
            r2m[mtl] = t0 - t1;                    // wire6: sign by r&2
            r1m[mtl] = (p0 - p1) + (p2 - p3);      // wire7: sign by r&1
        }
        float ps = am[0] + am[1];
        float m3 = am[0] - am[1];                  // wire3: bit4 = mtl
        float m6 = r2m[0] + r2m[1];
        float m7 = r1m[0] + r1m[1];
        float m0 = (wid & 4)  ? -ps : ps;          // wire0: bit7
        float m1 = (wid & 2)  ? -ps : ps;          // wire1: bit6
        float m2 = (wid & 1)  ? -ps : ps;          // wire2: bit5
        float m4 = (kgrp & 2) ? -ps : ps;          // wire4: bit3
        float m5 = (kgrp & 1) ? -ps : ps;          // wire5: bit2
        const int snt = nt * 16 + mrow;
        float* pp = &Ps[ct][snt * 9];
        pp[0]=m0; pp[1]=m1; pp[2]=m2; pp[3]=m3; pp[4]=m4; pp[5]=m5; pp[6]=m6; pp[7]=m7;
    }
    __syncthreads();
    if (tid < 64) {
        const int s    = tid & 31;
        const int half = tid >> 5;
        float r0 = 0.f, r1 = 0.f, r2 = 0.f, r3 = 0.f;
        #pragma unroll
        for (int uu = 0; uu < 32; ++uu) {
            const float* pp = &Ps[uu][s * 9 + half * 4];
            r0 += pp[0]; r1 += pp[1]; r2 += pp[2]; r3 += pp[3];
        }
        float4* o = (float4*)(out + (s0 + s) * 8 + half * 4);
        *o = make_float4(r0, r1, r2, r3);
    }
}

extern "C" void kernel_launch(void* const* d_in, const int* in_sizes, int n_in,
                              void* d_out, int out_size, void* d_ws, size_t ws_size,
                              hipStream_t stream)
{
    const float* x = (const float*)d_in[0];
    const float* w = (const float*)d_in[1];
    unsigned short* Ub = (unsigned short*)d_ws;   // 256 KiB
    ukern<<<64, 256, 0, stream>>>(w, Ub);
    qmain<<<256, 512, 0, stream>>>(x, w, Ub, (float*)d_out);
}

// Round 9
// 22.147 us; speedup vs baseline: 3.1400x; 1.0579x over previous
//
#include <hip/hip_runtime.h>

#define BATCH 8192

typedef __attribute__((ext_vector_type(8))) short bf16x8;
typedef __attribute__((ext_vector_type(4))) float f32x4;

__device__ __forceinline__ unsigned short f2bf(float f) {
    unsigned int u = __float_as_uint(f);
    u += 0x7fffu + ((u >> 16) & 1u);      // RTNE
    return (unsigned short)(u >> 16);
}
__device__ __forceinline__ float rdl(float v, int lane) {
    return __int_as_float(__builtin_amdgcn_readlane(__float_as_int(v), lane));
}

// ---------------------------------------------------------------------------
// Kernel 1: U columns, 256 blocks x 64 threads (1 column per block/wave).
// Lane bits l5..l0 = wires 0-5, reg bits k1k0 = wires 6,7 (R3/R5-verified).
// Coefficients computed ONCE up front, lane-distributed: lane t<32 owns
// (layer,wire)=(t>>3,t&7); gate loop fetches via readlane (no trig in chain).
// Ub[512][256] bf16: rows 0-255 Re, rows 256-511 Im; column c = basis state.
// ---------------------------------------------------------------------------
__global__ __launch_bounds__(64) void ukern(const float* __restrict__ w,
                                            unsigned short* __restrict__ Ub)
{
    const int l = threadIdx.x;
    const int c = blockIdx.x;

    // ---- upfront coefficients (identical math to R8 per-layer versions) ----
    float v0, v1, v2, v3;
    {
        const int t  = l & 31;
        const int li = t >> 3;
        const int wi = t & 7;
        float th = w[(li * 8 + wi) * 2 + 0];
        float ph = w[(li * 8 + wi) * 2 + 1];
        float cth = __cosf(0.5f * th), sth = __sinf(0.5f * th);
        if (wi < 6) {
            float cph = __cosf(0.5f * ph), sph = __sinf(0.5f * ph);
            v0 = cth * cph;   // Ar
            v1 = cth * sph;   // Ai magnitude
            v2 = sth * cph;   // Br magnitude
            v3 = sth * sph;   // SZ
        } else {
            v0 = cth;             // cy
            v1 = sth;             // sy
            v2 = __cosf(ph);      // cf
            v3 = __sinf(ph);      // sf
        }
    }

    float re[4], im[4];
    const bool ls = (l == (c >> 2));
    #pragma unroll
    for (int k = 0; k < 4; ++k) {
        re[k] = (ls && ((c & 3) == k)) ? 1.0f : 0.0f;
        im[k] = 0.0f;
    }
    const int  src = (l ^ (l >> 1)) & 63;
    const bool c5  = (l & 1);

    #pragma unroll
    for (int layer = 0; layer < 4; ++layer) {
        const int lb = layer * 8;
        // CNOT(0,1)..(4,5): lane permutation
        float tr[4], ti[4];
        #pragma unroll
        for (int k = 0; k < 4; ++k) {
            tr[k] = __shfl(re[k], src, 64);
            ti[k] = __shfl(im[k], src, 64);
        }
        // CNOT(5,6) + reg-Gray (CNOT 6,7)
        re[0] = c5 ? tr[2] : tr[0];  im[0] = c5 ? ti[2] : ti[0];
        re[1] = c5 ? tr[3] : tr[1];  im[1] = c5 ? ti[3] : ti[1];
        re[2] = c5 ? tr[1] : tr[3];  im[2] = c5 ? ti[1] : ti[3];
        re[3] = c5 ? tr[0] : tr[2];  im[3] = c5 ? ti[0] : ti[2];
        // CNOT(7,0)
        re[1] = __shfl_xor(re[1], 32, 64); im[1] = __shfl_xor(im[1], 32, 64);
        re[3] = __shfl_xor(re[3], 32, 64); im[3] = __shfl_xor(im[3], 32, 64);

        // fused RZ+RY on lane wires 0..5
        #pragma unroll
        for (int i = 0; i < 6; ++i) {
            float Ar = rdl(v0, lb + i);
            float SZ = rdl(v3, lb + i);
            float sgn = (l & (32 >> i)) ? 1.0f : -1.0f;
            float Ai = sgn * rdl(v1, lb + i);
            float Br = sgn * rdl(v2, lb + i);
            const int m = 32 >> i;
            #pragma unroll
            for (int k = 0; k < 4; ++k) {
                float br = __shfl_xor(re[k], m, 64);
                float bi = __shfl_xor(im[k], m, 64);
                float ar = re[k], ai = im[k];
                re[k] = Ar*ar - Ai*ai + Br*br + SZ*bi;
                im[k] = Ar*ai + Ai*ar + Br*bi - SZ*br;
            }
        }
        // reg wires 6,7: RZ = diag(1, e^{i ph}) then RY
        #pragma unroll
        for (int i = 0; i < 2; ++i) {
            float cy = rdl(v0, lb + 6 + i);
            float sy = rdl(v1, lb + 6 + i);
            float cf = rdl(v2, lb + 6 + i);
            float sf = rdl(v3, lb + 6 + i);
            const int mk = 2 >> i;
            #pragma unroll
            for (int k = 0; k < 4; ++k) {
                if (!(k & mk)) continue;
                float r = re[k], q = im[k];
                re[k] = r * cf - q * sf;
                im[k] = q * cf + r * sf;
            }
            #pragma unroll
            for (int k = 0; k < 4; ++k) {
                if (k & mk) continue;
                int k1 = k | mk;
                float ar = re[k], ai = im[k], br = re[k1], bi = im[k1];
                re[k]  = cy * ar - sy * br;
                im[k]  = cy * ai - sy * bi;
                re[k1] = sy * ar + cy * br;
                im[k1] = sy * ai + cy * bi;
            }
        }
    }
    #pragma unroll
    for (int k = 0; k < 4; ++k) {
        int i = l * 4 + k;
        Ub[i * 256 + c]         = f2bf(re[k]);
        Ub[(256 + i) * 256 + c] = f2bf(im[k]);
    }
}

// ---------------------------------------------------------------------------
// Kernel 2: 256 blocks x 512 threads (8 waves, 2/SIMD).
// Phase 0: trig once per (sample,wire) -> trg LDS.
// Phase 1: psi (32 samples x 256 amps bf16) in LDS.   [R8-verified]
// Phase 2: GEMM C[512][32] = U * psi, wave wid owns amps [32*wid,32*wid+32),
//          fused |.|^2 + signed-sum epilogue with in-wave kgrp reduction.
// Amp-index bit (7-w) = wire w: wid = bits 7..5, mtl = bit 4, kgrp = bits 3..2,
// r = bits 1..0.
// ---------------------------------------------------------------------------
__global__ __launch_bounds__(512) void qmain(const float* __restrict__ x,
                                             const float* __restrict__ w,
                                             const unsigned short* __restrict__ Ub,
                                             float* __restrict__ out)
{
    __shared__ float trg[32][17];              // [sample][wire]=cos, [8+wire]=sin
    __shared__ unsigned short psi[32 * 264];   // 32 samples x 256 amps, stride 264
    __shared__ float Ps[8][289];               // per-wave epilogue partials
    const int tid  = threadIdx.x;
    const int wid  = tid >> 6;
    const int lane = tid & 63;
    const int bid  = blockIdx.x;
    const int s0   = bid * 32;

    // ---- phase 0: trig, one (sample,wire) pair per thread ----
    if (tid < 256) {
        const int s  = tid >> 3;
        const int wi = tid & 7;
        float a = 0.5f * (x[(s0 + s) * 8 + wi] + w[2 * wi]);
        trg[s][wi]     = __cosf(a);
        trg[s][8 + wi] = __sinf(a);
    }
    __syncthreads();

    // ---- phase 1: psi chunk (16 amps) per thread ----
    {
        const int s  = tid >> 4;
        const int j1 = tid & 15;
        float c0 = trg[s][0], c1 = trg[s][1], c2 = trg[s][2], c3 = trg[s][3];
        float s0w = trg[s][8], s1w = trg[s][9], s2w = trg[s][10], s3w = trg[s][11];
        float A1 = ((j1 & 8) ? s0w : c0) * ((j1 & 4) ? s1w : c1)
                 * ((j1 & 2) ? s2w : c2) * ((j1 & 1) ? s3w : c3);
        float c4 = trg[s][4], c5 = trg[s][5], c6 = trg[s][6], c7 = trg[s][7];
        float s4 = trg[s][12], s5 = trg[s][13], s6 = trg[s][14], s7 = trg[s][15];
        float q45[4] = {A1 * c4 * c5, A1 * c4 * s5, A1 * s4 * c5, A1 * s4 * s5};
        float p67[4] = {c6 * c7, c6 * s7, s6 * c7, s6 * s7};
        unsigned int wbuf[8];
        #pragma unroll
        for (int p = 0; p < 8; ++p) {
            int ja = 2 * p, jb = 2 * p + 1;
            float va = q45[ja >> 2] * p67[ja & 3];
            float vb = q45[jb >> 2] * p67[jb & 3];
            wbuf[p] = (unsigned int)f2bf(va) | ((unsigned int)f2bf(vb) << 16);
        }
        uint4* dst = (uint4*)((char*)psi + s * 528 + j1 * 32);
        dst[0] = make_uint4(wbuf[0], wbuf[1], wbuf[2], wbuf[3]);
        dst[1] = make_uint4(wbuf[4], wbuf[5], wbuf[6], wbuf[7]);
    }
    __syncthreads();

    // ---- phase 2: GEMM, wave wid owns amps [32*wid, 32*wid+32) ----
    const int mrow = lane & 15;
    const int kgrp = lane >> 4;

    f32x4 acc[4][2];   // mt: 0,1 = Re tiles; 2,3 = Im tiles; nt 0..1
    #pragma unroll
    for (int a = 0; a < 4; ++a)
        #pragma unroll
        for (int b = 0; b < 2; ++b)
            acc[a][b] = (f32x4){0.f, 0.f, 0.f, 0.f};

    #pragma unroll
    for (int ks = 0; ks < 8; ++ks) {
        const int k0 = ks * 32 + kgrp * 8;
        bf16x8 bfr0 = *(const bf16x8*)(psi + mrow * 264 + k0);
        bf16x8 bfr1 = *(const bf16x8*)(psi + (16 + mrow) * 264 + k0);
        #pragma unroll
        for (int mt = 0; mt < 4; ++mt) {
            const int row = (mt < 2) ? (wid * 32 + mt * 16 + mrow)
                                     : (256 + wid * 32 + (mt - 2) * 16 + mrow);
            bf16x8 afr = *(const bf16x8*)(Ub + row * 256 + k0);
            acc[mt][0] = __builtin_amdgcn_mfma_f32_16x16x32_bf16(afr, bfr0, acc[mt][0], 0, 0, 0);
            acc[mt][1] = __builtin_amdgcn_mfma_f32_16x16x32_bf16(afr, bfr1, acc[mt][1], 0, 0, 0);
        }
    }

    // ---- epilogue: amp = 32*wid + mtl*16 + kgrp*4 + r; reduce kgrp in-wave ----
    #pragma unroll
    for (int nt = 0; nt < 2; ++nt) {
        float am[2], r2m[2], r1m[2];
        #pragma unroll
        for (int mtl = 0; mtl < 2; ++mtl) {
            float p0 = acc[mtl][nt][0]*acc[mtl][nt][0] + acc[mtl+2][nt][0]*acc[mtl+2][nt][0];
            float p1 = acc[mtl][nt][1]*acc[mtl][nt][1] + acc[mtl+2][nt][1]*acc[mtl+2][nt][1];
            float p2 = acc[mtl][nt][2]*acc[mtl][nt][2] + acc[mtl+2][nt][2]*acc[mtl+2][nt][2];
            float p3 = acc[mtl][nt][3]*acc[mtl][nt][3] + acc[mtl+2][nt][3]*acc[mtl+2][nt][3];
            float t0 = p0 + p1, t1 = p2 + p3;
            am[mtl]  = t0 + t1;
            r2m[mtl] = t0 - t1;                    // wire6: sign by r&2
            r1m[mtl] = (p0 - p1) + (p2 - p3);      // wire7: sign by r&1
        }
        float ps = am[0] + am[1];
        float m3 = am[0] - am[1];                  // wire3: bit4 = mtl
        float m6 = r2m[0] + r2m[1];
        float m7 = r1m[0] + r1m[1];
        float m0 = (wid & 4)  ? -ps : ps;          // wire0: bit7
        float m1 = (wid & 2)  ? -ps : ps;          // wire1: bit6
        float m2 = (wid & 1)  ? -ps : ps;          // wire2: bit5
        float m4 = (kgrp & 2) ? -ps : ps;          // wire4: bit3
        float m5 = (kgrp & 1) ? -ps : ps;          // wire5: bit2
        // reduce over kgrp (lane bits 4,5)
        m0 += __shfl_xor(m0, 16, 64);  m0 += __shfl_xor(m0, 32, 64);
        m1 += __shfl_xor(m1, 16, 64);  m1 += __shfl_xor(m1, 32, 64);
        m2 += __shfl_xor(m2, 16, 64);  m2 += __shfl_xor(m2, 32, 64);
        m3 += __shfl_xor(m3, 16, 64);  m3 += __shfl_xor(m3, 32, 64);
        m4 += __shfl_xor(m4, 16, 64);  m4 += __shfl_xor(m4, 32, 64);
        m5 += __shfl_xor(m5, 16, 64);  m5 += __shfl_xor(m5, 32, 64);
        m6 += __shfl_xor(m6, 16, 64);  m6 += __shfl_xor(m6, 32, 64);
        m7 += __shfl_xor(m7, 16, 64);  m7 += __shfl_xor(m7, 32, 64);
        if (kgrp == 0) {
            const int snt = nt * 16 + mrow;
            float* pp = &Ps[wid][snt * 9];
            pp[0]=m0; pp[1]=m1; pp[2]=m2; pp[3]=m3; pp[4]=m4; pp[5]=m5; pp[6]=m6; pp[7]=m7;
        }
    }
    __syncthreads();
    if (tid < 64) {
        const int s    = tid & 31;
        const int half = tid >> 5;
        float r0 = 0.f, r1 = 0.f, r2 = 0.f, r3 = 0.f;
        #pragma unroll
        for (int uu = 0; uu < 8; ++uu) {
            const float* pp = &Ps[uu][s * 9 + half * 4];
            r0 += pp[0]; r1 += pp[1]; r2 += pp[2]; r3 += pp[3];
        }
        float4* o = (float4*)(out + (s0 + s) * 8 + half * 4);
        *o = make_float4(r0, r1, r2, r3);
    }
}

extern "C" void kernel_launch(void* const* d_in, const int* in_sizes, int n_in,
                              void* d_out, int out_size, void* d_ws, size_t ws_size,
                              hipStream_t stream)
{
    const float* x = (const float*)d_in[0];
    const float* w = (const float*)d_in[1];
    unsigned short* Ub = (unsigned short*)d_ws;   // 256 KiB
    ukern<<<256, 64, 0, stream>>>(w, Ub);
    qmain<<<256, 512, 0, stream>>>(x, w, Ub, (float*)d_out);
}